// Round 9
// baseline (13064.369 us; speedup 1.0000x reference)
//
#include <hip/hip_runtime.h>
#include <cstdint>
#include <cstddef>
#include <math.h>

#define B_   32
#define S_   2048
#define IN_  128
#define H_   256
#define Q_   16
#define M_   64
#define D_   4      // layer-1 lag (aring depth 4: reads t-1 & t-3, write t -> distinct mod 4)

typedef unsigned long long u64;
typedef __attribute__((ext_vector_type(2))) unsigned int u32x2;

__device__ __forceinline__ float4 ld4(const float* p) { return *(const float4*)p; }

#define AGLD64(p)    __hip_atomic_load((p),  __ATOMIC_RELAXED, __HIP_MEMORY_SCOPE_AGENT)
#define AGST64(p, v) __hip_atomic_store((p), (v), __ATOMIC_RELAXED, __HIP_MEMORY_SCOPE_AGENT)

// Coalesced poll of ONE tagged u64. sc0 sc1 bypass L1/L2 -> observe the MALL
// (agent-atomic coherence point) with a normal coalescible load.
__device__ __forceinline__ u32x2 mall_load_u64(const u64* p) {
  u32x2 q;
  asm volatile("global_load_dwordx2 %0, %1, off sc0 sc1\n\ts_waitcnt vmcnt(0)"
               : "=v"(q) : "v"(p) : "memory");
  return q;
}
// Split issue/wait: first sample flies under the shadow work.
__device__ __forceinline__ void mall_issue1(const u64* p, u32x2& q) {
  asm volatile("global_load_dwordx2 %0, %1, off sc0 sc1"
               : "=&v"(q) : "v"(p) : "memory");
}
__device__ __forceinline__ void mall_wait1(u32x2& q) {
  asm volatile("s_waitcnt vmcnt(0)" : "+v"(q) :: "memory");
}

// fast sigmoid / tanh: exact identities on __expf (v_exp_f32), ~1e-7 abs err
__device__ __forceinline__ float sigm_f(float x) { return 1.0f / (1.0f + __expf(-x)); }
__device__ __forceinline__ float tanh_f(float x) { return 1.0f - 2.0f / (__expf(2.0f * x) + 1.0f); }

// ---------------------------------------------------------------------------
// Fused 2-layer LSTM recurrence, round-5 protocol, 2 waves/SIMD occupancy.
// 256 blocks = 32 rows x 8 col-groups; 512 THREADS (8 waves), 1 block/CU ->
// 2 waves/SIMD; per-SIMD partner waves hide each other's poll/LDS/exp stalls.
// ROUND-8 LESSON: __launch_bounds__(512,1) let the allocator target 4
// waves/EU (128-VGPR cap) -- an occupancy a single 8-wave block can never
// reach -- spilling the 160-float weight set to scratch (FETCH 1.1 GB,
// VGPR=128). Fix: pin waves/EU to the physically-realizable 2 -> 256-VGPR
// cap, weights stay register-resident. Health: VGPR 200-256, FETCH ~<450MB.
// Lane layout: wave w=tid>>6 (0..7), kc=l&15 (16-elem k-chunk), rg=l>>4
// (0..3), col = n*32 + w*4 + rg. Dots k-parallel: 4x ds_read_b128 + 4-step
// shfl_xor butterfly over 16 kc-lanes; gate/cell/act/publish in-lane.
// Exchange: u64 = (tag<<32)|fp32bits, parity-2 ring, AGST64 publish,
// per-ELEMENT gather (512 threads cover A/H planes), first sample issued
// before shadow work, 16 sc0sc1 retries, proven AGLD64 fallback, guard->dead.
// All-fp32 arithmetic (bf16 anywhere shifts kNN top-3 picks -> 0.46 absmax).
// ---------------------------------------------------------------------------
__global__ __launch_bounds__(512, 2) __attribute__((amdgpu_waves_per_eu(2, 2)))
void lstm2(
    const float* __restrict__ x,     // [B,S,128]
    const float* __restrict__ Wih0, const float* __restrict__ bih0,
    const float* __restrict__ bhh0, const float* __restrict__ Whh0,
    const float* __restrict__ Wih1, const float* __restrict__ bih1,
    const float* __restrict__ bhh1, const float* __restrict__ Whh1,
    float* __restrict__ out,         // [B,S,256]  (= d_out, layer-1 hidden)
    u64* __restrict__ exs)           // [32][2mat][2par][256] tagged u64
{
  const int f = blockIdx.x;
  const int n = f & 7;                     // col-group 0..7
  const int b = f >> 3;                    // row 0..31

  const int tid = threadIdx.x;
  const int w   = tid >> 6;                // wave 0..7
  const int l   = tid & 63;
  const int kc  = l & 15;                  // k-chunk lane 0..15 (16 elems)
  const int rg  = l >> 4;                  // col-in-wave 0..3
  const int wrg = w * 4 + rg;              // col-in-block 0..31
  const int col = n * 32 + wrg;            // global hidden col 0..255

  __shared__ float w1[128][257];           // Wih1 block slice, padded (131.6 KB)
  __shared__ float aring[4][256];          // layer-0 hidden ring (4 KB)
  __shared__ float hring[2][256];          // layer-1 hidden parity dbuf (2 KB)
  __shared__ float x_sh[2][IN_];           // (1 KB)  total ~135.5 KB

  for (int i = tid; i < 4 * 256; i += 512) ((float*)aring)[i] = 0.0f;
  for (int i = tid; i < 2 * 256; i += 512) ((float*)hring)[i] = 0.0f;

  // --- register weights, chunk layout k = 4*kc + 64*j + i  (160 floats) --
  float4 wf0[4][4], wf1[4][4], wi0[4][2];
  float rb0[4], rb1[4];
#pragma unroll
  for (int g = 0; g < 4; g++) {
    const int row = g * 256 + col;
    const float* p0 = Whh0 + (size_t)row * 256 + 4 * kc;
    const float* p1 = Whh1 + (size_t)row * 256 + 4 * kc;
    const float* pi = Wih0 + (size_t)row * 128 + 4 * kc;
#pragma unroll
    for (int j = 0; j < 4; j++) {
      wf0[g][j] = ld4(p0 + 64 * j);
      wf1[g][j] = ld4(p1 + 64 * j);
    }
#pragma unroll
    for (int j = 0; j < 2; j++) wi0[g][j] = ld4(pi + 64 * j);
    rb0[g] = bih0[row] + bhh0[row];
    rb1[g] = bih1[row] + bhh1[row];
    const float* pw = Wih1 + (size_t)row * 256 + 4 * kc;
    float* dst = &w1[g * 32 + wrg][4 * kc];
#pragma unroll
    for (int j = 0; j < 4; j++) *(float4*)(dst + 64 * j) = ld4(pw + 64 * j);
  }

  const float* xrow = x + (size_t)b * S_ * IN_;
  float* outp = out + (size_t)b * S_ * H_;
  u64* exb = exs + (size_t)b * 1024;       // [2mat][2par][256]

  if (tid < IN_) {
    x_sh[0][tid] = xrow[tid];
    x_sh[1][tid] = xrow[IN_ + tid];
  }
  float xreg = (tid < IN_) ? xrow[(size_t)2 * IN_ + tid] : 0.0f;
  float cst0 = 0.0f, cst1 = 0.0f;          // cell state (replicated / kc)
  float xa0s[4], xa1s[4] = {0, 0, 0, 0};
  __syncthreads();

  // xa0 for t=0
  {
    const float* xb = x_sh[0];
    float4 xv[2];
#pragma unroll
    for (int j = 0; j < 2; j++) xv[j] = ld4(xb + 4 * kc + 64 * j);
#pragma unroll
    for (int g = 0; g < 4; g++) {
      float4 s4 = {0, 0, 0, 0};
#pragma unroll
      for (int j = 0; j < 2; j++) {
        s4.x += wi0[g][j].x * xv[j].x; s4.y += wi0[g][j].y * xv[j].y;
        s4.z += wi0[g][j].z * xv[j].z; s4.w += wi0[g][j].w * xv[j].w;
      }
      float s = (s4.x + s4.y) + (s4.z + s4.w);
      s += __shfl_xor(s, 1); s += __shfl_xor(s, 2);
      s += __shfl_xor(s, 4); s += __shfl_xor(s, 8);
      xa0s[g] = s + rb0[g];
    }
  }

  bool dead = false;
  for (int t = 0; t < S_ + D_; ++t) {
    const bool doA = (t < S_);
    const int  u   = t - D_;
    const bool doH = (u >= 0);
    const int  pa = t & 1, ph = u & 1;
    const unsigned eA = (unsigned)(t + 1), eH = (unsigned)(u + 1);

    // ---- 0. x prefetch issued first ------------------------------------
    float xreg_n = 0.0f;
    if (tid < IN_ && t + 2 < S_) {
      int tn = (t + 3 < S_) ? t + 3 : S_ - 1;
      xreg_n = xrow[(size_t)tn * IN_ + tid];
    }

    // ---- 1. layer-0 dot + cell + publish (per wave, publish ASAP) ------
    if (doA) {
      const float* ap = aring[(t - 1) & 3];
      float4 av[4];
#pragma unroll
      for (int j = 0; j < 4; j++) av[j] = ld4(ap + 4 * kc + 64 * j);
      float gv[4];
#pragma unroll
      for (int g = 0; g < 4; g++) {
        float4 s4 = {0, 0, 0, 0};
#pragma unroll
        for (int j = 0; j < 4; j++) {
          s4.x += wf0[g][j].x * av[j].x; s4.y += wf0[g][j].y * av[j].y;
          s4.z += wf0[g][j].z * av[j].z; s4.w += wf0[g][j].w * av[j].w;
        }
        float s = (s4.x + s4.y) + (s4.z + s4.w);
        s += __shfl_xor(s, 1); s += __shfl_xor(s, 2);
        s += __shfl_xor(s, 4); s += __shfl_xor(s, 8);
        gv[g] = s + xa0s[g];
      }
      float ig = sigm_f(gv[0]), fg = sigm_f(gv[1]);
      float cg = tanh_f(gv[2]), og = sigm_f(gv[3]);
      cst0 = fg * cst0 + ig * cg;
      float a = og * tanh_f(cst0);
      if (kc == 0) {                       // 4 lanes/wave publish own cols
        u64 pk = ((u64)eA << 32) | (u64)__float_as_uint(a);
        AGST64(exb + (pa << 8) + col, pk);
        aring[t & 3][col] = a;             // own cols stay local
      }
    }
    // ---- 2. layer-1 dot + cell + publish(+out) -------------------------
    if (doH) {
      const float* hp = hring[(u - 1) & 1];
      float4 hv[4];
#pragma unroll
      for (int j = 0; j < 4; j++) hv[j] = ld4(hp + 4 * kc + 64 * j);
      float gv[4];
#pragma unroll
      for (int g = 0; g < 4; g++) {
        float4 s4 = {0, 0, 0, 0};
#pragma unroll
        for (int j = 0; j < 4; j++) {
          s4.x += wf1[g][j].x * hv[j].x; s4.y += wf1[g][j].y * hv[j].y;
          s4.z += wf1[g][j].z * hv[j].z; s4.w += wf1[g][j].w * hv[j].w;
        }
        float s = (s4.x + s4.y) + (s4.z + s4.w);
        s += __shfl_xor(s, 1); s += __shfl_xor(s, 2);
        s += __shfl_xor(s, 4); s += __shfl_xor(s, 8);
        gv[g] = s + xa1s[g];
      }
      float ig = sigm_f(gv[0]), fg = sigm_f(gv[1]);
      float cg = tanh_f(gv[2]), og = sigm_f(gv[3]);
      cst1 = fg * cst1 + ig * cg;
      float h = og * tanh_f(cst1);
      if (kc == 0) {
        u64 pk = ((u64)eH << 32) | (u64)__float_as_uint(h);
        AGST64(exb + ((2 + ph) << 8) + col, pk);
        outp[(size_t)u * H_ + col] = h;
        hring[u & 1][col] = h;
      }
    }

    // ---- 3. issue gather first samples (fly under shadow work) ---------
    const bool isA = (tid < 256);
    const int  e   = tid & 255;
    const bool ownp = ((e >> 5) == n);
    const bool act  = isA ? doA : doH;
    const bool need = act && !ownp && !dead;
    const unsigned etag = isA ? eA : eH;
    const int plane = isA ? pa : 2 + ph;
    u64* bp = exb + (plane << 8) + e;
    u32x2 q;
    if (need) mall_issue1(bp, q);

    // ---- 4. off-critical-path work (overlaps exchange latency) ---------
    if (t + 1 < S_) {
      const float* xb = x_sh[(t + 1) & 1];
      float4 xv[2];
#pragma unroll
      for (int j = 0; j < 2; j++) xv[j] = ld4(xb + 4 * kc + 64 * j);
#pragma unroll
      for (int g = 0; g < 4; g++) {
        float4 s4 = {0, 0, 0, 0};
#pragma unroll
        for (int j = 0; j < 2; j++) {
          s4.x += wi0[g][j].x * xv[j].x; s4.y += wi0[g][j].y * xv[j].y;
          s4.z += wi0[g][j].z * xv[j].z; s4.w += wi0[g][j].w * xv[j].w;
        }
        float s = (s4.x + s4.y) + (s4.z + s4.w);
        s += __shfl_xor(s, 1); s += __shfl_xor(s, 2);
        s += __shfl_xor(s, 4); s += __shfl_xor(s, 8);
        xa0s[g] = s + rb0[g];
      }
    }
    {
      const int v = t - D_ + 1;
      if (v >= 0 && v < S_) {
        const float* avp = aring[v & 3];
        float4 av[4];
#pragma unroll
        for (int j = 0; j < 4; j++) av[j] = ld4(avp + 4 * kc + 64 * j);
#pragma unroll
        for (int g = 0; g < 4; g++) {
          const float* wr = &w1[g * 32 + wrg][4 * kc];
          float4 s4 = {0, 0, 0, 0};
#pragma unroll
          for (int j = 0; j < 4; j++) {
            float4 wv = ld4(wr + 64 * j);
            s4.x += wv.x * av[j].x; s4.y += wv.y * av[j].y;
            s4.z += wv.z * av[j].z; s4.w += wv.w * av[j].w;
          }
          float s = (s4.x + s4.y) + (s4.z + s4.w);
          s += __shfl_xor(s, 1); s += __shfl_xor(s, 2);
          s += __shfl_xor(s, 4); s += __shfl_xor(s, 8);
          xa1s[g] = s + rb1[g];
        }
      }
    }

    // ---- 5. wait, check, bounded retries, proven fallback --------------
    if (need) {
      mall_wait1(q);
      bool got = (q.y == etag);
#pragma unroll 1
      for (int it = 0; it < 16 && !got; ++it) {
        q = mall_load_u64(bp);
        got = (q.y == etag);
      }
      if (!got) {                          // proven coherent fallback
        unsigned guard = 0;
        while (!got) {
          u64 v2 = AGLD64(bp);
          if ((unsigned)(v2 >> 32) == etag) { q.x = (unsigned)v2; got = true; }
          if (++guard >= (1u << 20)) { dead = true; break; }
        }
      }
      if (isA) aring[t & 3][e] = __uint_as_float(q.x);
      else     hring[u & 1][e] = __uint_as_float(q.x);
    }

    if (tid < IN_ && t < S_) x_sh[t & 1][tid] = xreg;
    xreg = xreg_n;
    __syncthreads();
  }
}

// ---------------------------------------------------------------------------
// kNN memory read. One wave per token. enh = qw * enhanced  [MT,256] fp32.
// ---------------------------------------------------------------------------
__global__ __launch_bounds__(256) void knn_enh(
    const float* __restrict__ lstm, const float* __restrict__ Wcq,
    const float* __restrict__ bcq, const float* __restrict__ keys,
    const float* __restrict__ vals, const float* __restrict__ qwp,
    float* __restrict__ enh)
{
  const int tid  = threadIdx.x;
  const int wave = tid >> 6, lane = tid & 63;
  const int t = blockIdx.x * 4 + wave;

  __shared__ float xsh[4][256];
  __shared__ float qsh[4][16];

  const float* xrow = lstm + (size_t)t * H_;
  float4 x4 = ld4(xrow + lane * 4);
  *(float4*)&xsh[wave][lane * 4] = x4;
  __syncthreads();

  const int j = lane & 15, seg = lane >> 4;
  const float* wrow = Wcq + j * H_ + seg * 64;
  const float* xseg = &xsh[wave][seg * 64];
  float p = 0.0f;
#pragma unroll
  for (int c = 0; c < 64; c += 4) {
    float4 w4 = ld4(wrow + c);
    p += w4.x * xseg[c] + w4.y * xseg[c + 1] + w4.z * xseg[c + 2] + w4.w * xseg[c + 3];
  }
  p += __shfl_xor(p, 16);
  p += __shfl_xor(p, 32);
  float q = tanhf(p + bcq[j]);

  float sq = q * q;
  sq += __shfl_xor(sq, 1); sq += __shfl_xor(sq, 2);
  sq += __shfl_xor(sq, 4); sq += __shfl_xor(sq, 8);
  float qn = q / (sqrtf(sq) + 1e-8f);
  if (lane < 16) qsh[wave][lane] = qn;
  __syncthreads();

  const int m = lane;
  const float* krow = keys + m * Q_;
  float kv[16]; float kn2 = 0.0f;
#pragma unroll
  for (int jj = 0; jj < 16; jj++) { kv[jj] = krow[jj]; kn2 += kv[jj] * kv[jj]; }
  float rn = 1.0f / (sqrtf(kn2) + 1e-8f);
  float sim = 0.0f;
#pragma unroll
  for (int jj = 0; jj < 16; jj++) sim += qsh[wave][jj] * kv[jj];
  sim *= rn;

  float rem = sim;
  float tv[3]; int ti[3];
#pragma unroll
  for (int k = 0; k < 3; k++) {
    float v = rem; int idx = m;
#pragma unroll
    for (int d = 1; d < 64; d <<= 1) {
      float ov = __shfl_xor(v, d);
      int   oi = __shfl_xor(idx, d);
      if (ov > v || (ov == v && oi < idx)) { v = ov; idx = oi; }
    }
    tv[k] = v; ti[k] = idx;
    if (m == idx) rem = -INFINITY;
  }
  float tot = tv[0] + tv[1] + tv[2];

  float ex = 0, ey = 0, ez = 0, ew = 0;
#pragma unroll
  for (int k = 0; k < 3; k++) {
    float4 vv = ld4(vals + (size_t)ti[k] * H_ + lane * 4);
    ex += tv[k] * vv.x; ey += tv[k] * vv.y;
    ez += tv[k] * vv.z; ew += tv[k] * vv.w;
  }
  float inv = (tot > 0.0f) ? 1.0f / tot : 0.0f;
  const float qw = qwp[0];

  float4 o;
  o.x = qw * ex * inv; o.y = qw * ey * inv;
  o.z = qw * ez * inv; o.w = qw * ew * inv;
  *(float4*)&enh[(size_t)t * H_ + lane * 4] = o;
}

// ---------------------------------------------------------------------------
// Final projection, IN-PLACE on io (= d_out). Block owns 64 rows x all 256
// cols; reads its own rows, writes after the K-loop -> race-free in-place.
// ---------------------------------------------------------------------------
__global__ __launch_bounds__(256) void gemm_cat(
    float* __restrict__ io, const float* __restrict__ A2,
    const float* __restrict__ Bw, const float* __restrict__ bias,
    const float* __restrict__ cwp)
{
  __shared__ float As[16][68];
  __shared__ float Bs[16][260];
  const int tid  = threadIdx.x;
  const int row0 = blockIdx.x * 64;
  const int tx = tid & 15, ty = tid >> 4;
  const int lr = tid >> 2;
  const int lk = (tid & 3) << 2;
  const float cw = cwp[0];

  float acc[4][16];
#pragma unroll
  for (int i = 0; i < 4; i++)
#pragma unroll
    for (int j = 0; j < 16; j++) acc[i][j] = 0.0f;

  for (int k0 = 0; k0 < 512; k0 += 16) {
    float4 av;
    if (k0 < 256) {
      av = ld4(io + (size_t)(row0 + lr) * 256 + k0 + lk);
      av.x *= cw; av.y *= cw; av.z *= cw; av.w *= cw;
    } else {
      av = ld4(A2 + (size_t)(row0 + lr) * 256 + (k0 - 256) + lk);
    }
    As[lk + 0][lr] = av.x; As[lk + 1][lr] = av.y;
    As[lk + 2][lr] = av.z; As[lk + 3][lr] = av.w;
    const float* bp = Bw + (size_t)tid * 512 + k0;
#pragma unroll
    for (int q = 0; q < 4; q++) {
      float4 b4 = ld4(bp + 4 * q);
      Bs[4 * q + 0][tid] = b4.x; Bs[4 * q + 1][tid] = b4.y;
      Bs[4 * q + 2][tid] = b4.z; Bs[4 * q + 3][tid] = b4.w;
    }
    __syncthreads();
#pragma unroll
    for (int k = 0; k < 16; k++) {
      float4 a4 = *(const float4*)&As[k][ty << 2];
      float aa[4] = {a4.x, a4.y, a4.z, a4.w};
#pragma unroll
      for (int cc = 0; cc < 4; cc++) {
        float4 b4 = *(const float4*)&Bs[k][cc * 64 + (tx << 2)];
        float bb[4] = {b4.x, b4.y, b4.z, b4.w};
#pragma unroll
        for (int i = 0; i < 4; i++)
#pragma unroll
          for (int jj = 0; jj < 4; jj++) acc[i][cc * 4 + jj] += aa[i] * bb[jj];
      }
    }
    __syncthreads();
  }

#pragma unroll
  for (int i = 0; i < 4; i++) {
#pragma unroll
    for (int cc = 0; cc < 4; cc++) {
      int c0 = cc * 64 + (tx << 2);
      float4 o;
      o.x = acc[i][cc * 4 + 0] + bias[c0 + 0];
      o.y = acc[i][cc * 4 + 1] + bias[c0 + 1];
      o.z = acc[i][cc * 4 + 2] + bias[c0 + 2];
      o.w = acc[i][cc * 4 + 3] + bias[c0 + 3];
      *(float4*)&io[(size_t)(row0 + (ty << 2) + i) * 256 + c0] = o;
    }
  }
}

// ---------------------------------------------------------------------------
extern "C" void kernel_launch(void* const* d_in, const int* in_sizes, int n_in,
                              void* d_out, int out_size, void* d_ws, size_t ws_size,
                              hipStream_t stream)
{
  const float* x    = (const float*)d_in[0];
  const float* Wih0 = (const float*)d_in[1];
  const float* Whh0 = (const float*)d_in[2];
  const float* bih0 = (const float*)d_in[3];
  const float* bhh0 = (const float*)d_in[4];
  const float* Wih1 = (const float*)d_in[5];
  const float* Whh1 = (const float*)d_in[6];
  const float* bih1 = (const float*)d_in[7];
  const float* bhh1 = (const float*)d_in[8];
  const float* Wcq  = (const float*)d_in[9];
  const float* bcq  = (const float*)d_in[10];
  const float* keys = (const float*)d_in[11];
  const float* vals = (const float*)d_in[12];
  const float* Wout = (const float*)d_in[13];
  const float* bout = (const float*)d_in[14];
  const float* cw   = (const float*)d_in[15];
  const float* qw   = (const float*)d_in[16];
  float* out = (float*)d_out;

  // ws: [exchange 256 KB (dead after lstm2)] overlapped with enh [MT,256] f32.
  const size_t HE = (size_t)B_ * S_ * H_;
  if (ws_size < HE * sizeof(float)) return;   // 67.1 MB (round-4 proven OK)
  u64* exs = (u64*)d_ws;
  float* enh = (float*)d_ws;

  const int MT = B_ * S_;

  hipMemsetAsync(exs, 0, (size_t)32 * 1024 * sizeof(u64), stream);
  lstm2<<<dim3(256), dim3(512), 0, stream>>>(x, Wih0, bih0, bhh0, Whh0,
                                             Wih1, bih1, bhh1, Whh1, out, exs);

  knn_enh<<<dim3(MT / 4), dim3(256), 0, stream>>>(out, Wcq, bcq, keys, vals, qw, enh);

  gemm_cat<<<dim3(MT / 64), dim3(256), 0, stream>>>(out, enh, Wout, bout, cw);
}

// Round 10
// 12888.339 us; speedup vs baseline: 1.0137x; 1.0137x over previous
//
#include <hip/hip_runtime.h>
#include <cstdint>
#include <cstddef>
#include <math.h>

#define B_   32
#define S_   2048
#define IN_  128
#define H_   256
#define Q_   16
#define M_   64
#define D_   4      // layer-1 lag (aring depth 4: reads t-1 & t-3, write t -> distinct mod 4)

typedef unsigned long long u64;
typedef __attribute__((ext_vector_type(4))) unsigned int u32x4;

__device__ __forceinline__ float4 ld4(const float* p) { return *(const float4*)p; }

#define AGLD64(p)    __hip_atomic_load((p),  __ATOMIC_RELAXED, __HIP_MEMORY_SCOPE_AGENT)
#define AGST64(p, v) __hip_atomic_store((p), (v), __ATOMIC_RELAXED, __HIP_MEMORY_SCOPE_AGENT)

// fast sigmoid / tanh: exact identities on __expf (v_exp_f32), ~1e-7 abs err
__device__ __forceinline__ float sigm_f(float x) { return 1.0f / (1.0f + __expf(-x)); }
__device__ __forceinline__ float tanh_f(float x) { return 1.0f - 2.0f / (__expf(2.0f * x) + 1.0f); }

// ---------------------------------------------------------------------------
// Fused 2-layer LSTM recurrence. 512 blocks = 32 rows x 16 col-groups,
// 256 threads (4 waves), 2 blocks/CU -> TRUE 2 waves/SIMD with honored
// registers (round-8/9 lesson: 512-thread blocks get VGPR capped at 128 ->
// AGPR-shuffle/spill, FETCH 1.1GB; 256-thread blocks honor ~224, r5).
// Block owns 16 hidden cols of BOTH layers. Per-lane weights 160 floats
// (wf0 64 + wf1 64 + wi0 32), Wih1 slice (64x256) in LDS. Lane layout:
// wave w=tid>>6 (0..3), kc=l&15 (16-elem k-chunk), rg=l>>4 (0..3),
// col = n*16 + w*4 + rg. Dots k-parallel: 4x ds_read_b128 + 4-step
// shfl_xor butterfly over 16 kc-lanes; gate/cell/act/publish in-lane.
// Exchange: u64 = (tag<<32)|fp32bits, parity-2 ring, AGST64 publish.
// GATHER (the measured 10k-cy/step term): waves 0-1 poll A-plane PAIRS,
// waves 2-3 H-plane PAIRS, with a PIPELINED 2-deep sc0sc1 sampler
// (counted vmcnt(1), alternating quad buffers, "+v" ordering) -> sample
// period ~RT/2 instead of serialized full-RT retries. One vmcnt(0) drain
// after publishes makes the counted waits exact (out-store & x-prefetch
// moved post-poll so they can't pollute the count). 24 fast samples, then
// the proven AGLD64 serial fallback, guard->dead (protocol unchanged).
// All-fp32 arithmetic (bf16 anywhere shifts kNN top-3 picks -> 0.46 absmax).
// ---------------------------------------------------------------------------
__global__ __launch_bounds__(256, 2) void lstm2(
    const float* __restrict__ x,     // [B,S,128]
    const float* __restrict__ Wih0, const float* __restrict__ bih0,
    const float* __restrict__ bhh0, const float* __restrict__ Whh0,
    const float* __restrict__ Wih1, const float* __restrict__ bih1,
    const float* __restrict__ bhh1, const float* __restrict__ Whh1,
    float* __restrict__ out,         // [B,S,256]  (= d_out, layer-1 hidden)
    u64* __restrict__ exs)           // [32][2mat][2par][256] tagged u64
{
  const int f = blockIdx.x;
  const int n = f & 15;                    // col-group 0..15
  const int b = f >> 4;                    // row 0..31

  const int tid = threadIdx.x;
  const int w   = tid >> 6;                // wave 0..3
  const int l   = tid & 63;
  const int kc  = l & 15;                  // k-chunk lane 0..15 (16 elems)
  const int rg  = l >> 4;                  // col-in-wave 0..3
  const int wrg = w * 4 + rg;              // col-in-block 0..15
  const int col = n * 16 + wrg;            // global hidden col 0..255

  __shared__ float w1[64][257];            // Wih1 block slice, padded (65.8 KB)
  __shared__ float aring[4][256];          // layer-0 hidden ring (4 KB)
  __shared__ float hring[2][256];          // layer-1 hidden parity dbuf (2 KB)
  __shared__ float x_sh[2][IN_];           // (1 KB)  total ~73 KB -> 2/CU

  for (int i = tid; i < 4 * 256; i += 256) ((float*)aring)[i] = 0.0f;
  for (int i = tid; i < 2 * 256; i += 256) ((float*)hring)[i] = 0.0f;

  // --- register weights, chunk layout k = 4*kc + 64*j + i  (160 floats) --
  float4 wf0[4][4], wf1[4][4], wi0[4][2];
  float rb0[4], rb1[4];
#pragma unroll
  for (int g = 0; g < 4; g++) {
    const int row = g * 256 + col;
    const float* p0 = Whh0 + (size_t)row * 256 + 4 * kc;
    const float* p1 = Whh1 + (size_t)row * 256 + 4 * kc;
    const float* pi = Wih0 + (size_t)row * 128 + 4 * kc;
#pragma unroll
    for (int j = 0; j < 4; j++) {
      wf0[g][j] = ld4(p0 + 64 * j);
      wf1[g][j] = ld4(p1 + 64 * j);
    }
#pragma unroll
    for (int j = 0; j < 2; j++) wi0[g][j] = ld4(pi + 64 * j);
    rb0[g] = bih0[row] + bhh0[row];
    rb1[g] = bih1[row] + bhh1[row];
    const float* pw = Wih1 + (size_t)row * 256 + 4 * kc;
    float* dst = &w1[g * 16 + wrg][4 * kc];
#pragma unroll
    for (int j = 0; j < 4; j++) *(float4*)(dst + 64 * j) = ld4(pw + 64 * j);
  }

  const float* xrow = x + (size_t)b * S_ * IN_;
  float* outp = out + (size_t)b * S_ * H_;
  u64* exb = exs + (size_t)b * 1024;       // [2mat][2par][256]

  if (tid < IN_) {
    x_sh[0][tid] = xrow[tid];
    x_sh[1][tid] = xrow[IN_ + tid];
  }
  float xreg = (tid < IN_) ? xrow[(size_t)2 * IN_ + tid] : 0.0f;
  float cst0 = 0.0f, cst1 = 0.0f;          // cell state (replicated / kc)
  float xa0s[4], xa1s[4] = {0, 0, 0, 0};
  __syncthreads();

  // xa0 for t=0
  {
    const float* xb = x_sh[0];
    float4 xv[2];
#pragma unroll
    for (int j = 0; j < 2; j++) xv[j] = ld4(xb + 4 * kc + 64 * j);
#pragma unroll
    for (int g = 0; g < 4; g++) {
      float4 s4 = {0, 0, 0, 0};
#pragma unroll
      for (int j = 0; j < 2; j++) {
        s4.x += wi0[g][j].x * xv[j].x; s4.y += wi0[g][j].y * xv[j].y;
        s4.z += wi0[g][j].z * xv[j].z; s4.w += wi0[g][j].w * xv[j].w;
      }
      float s = (s4.x + s4.y) + (s4.z + s4.w);
      s += __shfl_xor(s, 1); s += __shfl_xor(s, 2);
      s += __shfl_xor(s, 4); s += __shfl_xor(s, 8);
      xa0s[g] = s + rb0[g];
    }
  }

  const bool isA = (tid < 128);            // waves 0-1: A-plane; 2-3: H-plane
  const int  pi  = tid & 127;              // pair index 0..127
  bool dead = false;
  for (int t = 0; t < S_ + D_; ++t) {
    const bool doA = (t < S_);
    const int  u   = t - D_;
    const bool doH = (u >= 0);
    const int  pa = t & 1, ph = u & 1;
    const unsigned eA = (unsigned)(t + 1), eH = (unsigned)(u + 1);

    // ---- 1. layer-0 dot + cell + publish --------------------------------
    if (doA) {
      const float* ap = aring[(t - 1) & 3];
      float4 av[4];
#pragma unroll
      for (int j = 0; j < 4; j++) av[j] = ld4(ap + 4 * kc + 64 * j);
      float gv[4];
#pragma unroll
      for (int g = 0; g < 4; g++) {
        float4 s4 = {0, 0, 0, 0};
#pragma unroll
        for (int j = 0; j < 4; j++) {
          s4.x += wf0[g][j].x * av[j].x; s4.y += wf0[g][j].y * av[j].y;
          s4.z += wf0[g][j].z * av[j].z; s4.w += wf0[g][j].w * av[j].w;
        }
        float s = (s4.x + s4.y) + (s4.z + s4.w);
        s += __shfl_xor(s, 1); s += __shfl_xor(s, 2);
        s += __shfl_xor(s, 4); s += __shfl_xor(s, 8);
        gv[g] = s + xa0s[g];
      }
      float ig = sigm_f(gv[0]), fg = sigm_f(gv[1]);
      float cg = tanh_f(gv[2]), og = sigm_f(gv[3]);
      cst0 = fg * cst0 + ig * cg;
      float a = og * tanh_f(cst0);
      if (kc == 0) {
        u64 pk = ((u64)eA << 32) | (u64)__float_as_uint(a);
        AGST64(exb + (pa << 8) + col, pk);
      }
    }
    // ---- 2. layer-1 dot + cell + publish (out-store deferred) -----------
    float hval = 0.0f;
    if (doH) {
      const float* hp = hring[(u - 1) & 1];
      float4 hv[4];
#pragma unroll
      for (int j = 0; j < 4; j++) hv[j] = ld4(hp + 4 * kc + 64 * j);
      float gv[4];
#pragma unroll
      for (int g = 0; g < 4; g++) {
        float4 s4 = {0, 0, 0, 0};
#pragma unroll
        for (int j = 0; j < 4; j++) {
          s4.x += wf1[g][j].x * hv[j].x; s4.y += wf1[g][j].y * hv[j].y;
          s4.z += wf1[g][j].z * hv[j].z; s4.w += wf1[g][j].w * hv[j].w;
        }
        float s = (s4.x + s4.y) + (s4.z + s4.w);
        s += __shfl_xor(s, 1); s += __shfl_xor(s, 2);
        s += __shfl_xor(s, 4); s += __shfl_xor(s, 8);
        gv[g] = s + xa1s[g];
      }
      float ig = sigm_f(gv[0]), fg = sigm_f(gv[1]);
      float cg = tanh_f(gv[2]), og = sigm_f(gv[3]);
      cst1 = fg * cst1 + ig * cg;
      hval = og * tanh_f(cst1);
      if (kc == 0) {
        u64 pk = ((u64)eH << 32) | (u64)__float_as_uint(hval);
        AGST64(exb + ((2 + ph) << 8) + col, pk);
      }
    }

    // ---- 3. shadow work (overlaps publish propagation) ------------------
    if (t + 1 < S_) {
      const float* xb = x_sh[(t + 1) & 1];
      float4 xv[2];
#pragma unroll
      for (int j = 0; j < 2; j++) xv[j] = ld4(xb + 4 * kc + 64 * j);
#pragma unroll
      for (int g = 0; g < 4; g++) {
        float4 s4 = {0, 0, 0, 0};
#pragma unroll
        for (int j = 0; j < 2; j++) {
          s4.x += wi0[g][j].x * xv[j].x; s4.y += wi0[g][j].y * xv[j].y;
          s4.z += wi0[g][j].z * xv[j].z; s4.w += wi0[g][j].w * xv[j].w;
        }
        float s = (s4.x + s4.y) + (s4.z + s4.w);
        s += __shfl_xor(s, 1); s += __shfl_xor(s, 2);
        s += __shfl_xor(s, 4); s += __shfl_xor(s, 8);
        xa0s[g] = s + rb0[g];
      }
    }
    {
      const int v = t - D_ + 1;
      if (v >= 0 && v < S_) {
        const float* avp = aring[v & 3];
        float4 av[4];
#pragma unroll
        for (int j = 0; j < 4; j++) av[j] = ld4(avp + 4 * kc + 64 * j);
#pragma unroll
        for (int g = 0; g < 4; g++) {
          const float* wr = &w1[g * 16 + wrg][4 * kc];
          float4 s4 = {0, 0, 0, 0};
#pragma unroll
          for (int j = 0; j < 4; j++) {
            float4 wv = ld4(wr + 64 * j);
            s4.x += wv.x * av[j].x; s4.y += wv.y * av[j].y;
            s4.z += wv.z * av[j].z; s4.w += wv.w * av[j].w;
          }
          float s = (s4.x + s4.y) + (s4.z + s4.w);
          s += __shfl_xor(s, 1); s += __shfl_xor(s, 2);
          s += __shfl_xor(s, 4); s += __shfl_xor(s, 8);
          xa1s[g] = s + rb1[g];
        }
      }
    }

    // ---- 4. gather: pipelined 2-deep sampler + proven fallback ----------
    {
      const bool active = isA ? doA : doH;
      if (active && !dead) {
        u64* bp = exb + ((isA ? pa : (2 + ph)) << 8) + 2 * pi;
        const unsigned et = isA ? eA : eH;
        unsigned v0 = 0, v1 = 0;
        bool got = false;
        u32x4 q0, q1;
        // drain publishes (+ strays) so counted vmcnt below is exact
        asm volatile("s_waitcnt vmcnt(0)" ::: "memory");
        asm volatile("global_load_dwordx4 %0, %1, off sc0 sc1"
                     : "=&v"(q0) : "v"(bp) : "memory");
#pragma unroll 1
        for (int it = 0; it < 12; ++it) {
          asm volatile("global_load_dwordx4 %0, %1, off sc0 sc1"
                       : "=&v"(q1) : "v"(bp) : "memory");
          asm volatile("s_waitcnt vmcnt(1)" : "+v"(q0) :: "memory");
          if (!got && q0.y == et && q0.w == et) { v0 = q0.x; v1 = q0.z; got = true; }
          if (__all(got)) { asm volatile("s_waitcnt vmcnt(0)" : "+v"(q1) :: "memory"); break; }
          asm volatile("global_load_dwordx4 %0, %1, off sc0 sc1"
                       : "=&v"(q0) : "v"(bp) : "memory");
          asm volatile("s_waitcnt vmcnt(1)" : "+v"(q1) :: "memory");
          if (!got && q1.y == et && q1.w == et) { v0 = q1.x; v1 = q1.z; got = true; }
          if (__all(got)) { asm volatile("s_waitcnt vmcnt(0)" : "+v"(q0) :: "memory"); break; }
        }
        if (!__all(got)) asm volatile("s_waitcnt vmcnt(0)" ::: "memory");
        if (!got) {                        // proven coherent fallback
          unsigned guard = 0; bool g0 = false, g1 = false;
          while (!(g0 && g1)) {
            if (!g0) { u64 w0 = AGLD64(bp);     if ((unsigned)(w0 >> 32) == et) { v0 = (unsigned)w0; g0 = true; } }
            if (!g1) { u64 w1 = AGLD64(bp + 1); if ((unsigned)(w1 >> 32) == et) { v1 = (unsigned)w1; g1 = true; } }
            if (++guard >= (1u << 20)) { dead = true; break; }
          }
        }
        if (isA) {
          aring[t & 3][2 * pi]     = __uint_as_float(v0);
          aring[t & 3][2 * pi + 1] = __uint_as_float(v1);
        } else {
          hring[u & 1][2 * pi]     = __uint_as_float(v0);
          hring[u & 1][2 * pi + 1] = __uint_as_float(v1);
        }
      }
    }

    // ---- 5. deferred stores + x pipeline (post-poll: keep vmcnt clean) --
    if (doH && kc == 0) outp[(size_t)u * H_ + col] = hval;
    if (tid < IN_ && t < S_) x_sh[t & 1][tid] = xreg;
    if (tid < IN_ && t + 2 < S_) {
      int tn = (t + 3 < S_) ? t + 3 : S_ - 1;
      xreg = xrow[(size_t)tn * IN_ + tid];
    }
    __syncthreads();
  }
}

// ---------------------------------------------------------------------------
// kNN memory read. One wave per token. enh = qw * enhanced  [MT,256] fp32.
// ---------------------------------------------------------------------------
__global__ __launch_bounds__(256) void knn_enh(
    const float* __restrict__ lstm, const float* __restrict__ Wcq,
    const float* __restrict__ bcq, const float* __restrict__ keys,
    const float* __restrict__ vals, const float* __restrict__ qwp,
    float* __restrict__ enh)
{
  const int tid  = threadIdx.x;
  const int wave = tid >> 6, lane = tid & 63;
  const int t = blockIdx.x * 4 + wave;

  __shared__ float xsh[4][256];
  __shared__ float qsh[4][16];

  const float* xrow = lstm + (size_t)t * H_;
  float4 x4 = ld4(xrow + lane * 4);
  *(float4*)&xsh[wave][lane * 4] = x4;
  __syncthreads();

  const int j = lane & 15, seg = lane >> 4;
  const float* wrow = Wcq + j * H_ + seg * 64;
  const float* xseg = &xsh[wave][seg * 64];
  float p = 0.0f;
#pragma unroll
  for (int c = 0; c < 64; c += 4) {
    float4 w4 = ld4(wrow + c);
    p += w4.x * xseg[c] + w4.y * xseg[c + 1] + w4.z * xseg[c + 2] + w4.w * xseg[c + 3];
  }
  p += __shfl_xor(p, 16);
  p += __shfl_xor(p, 32);
  float q = tanhf(p + bcq[j]);

  float sq = q * q;
  sq += __shfl_xor(sq, 1); sq += __shfl_xor(sq, 2);
  sq += __shfl_xor(sq, 4); sq += __shfl_xor(sq, 8);
  float qn = q / (sqrtf(sq) + 1e-8f);
  if (lane < 16) qsh[wave][lane] = qn;
  __syncthreads();

  const int m = lane;
  const float* krow = keys + m * Q_;
  float kv[16]; float kn2 = 0.0f;
#pragma unroll
  for (int jj = 0; jj < 16; jj++) { kv[jj] = krow[jj]; kn2 += kv[jj] * kv[jj]; }
  float rn = 1.0f / (sqrtf(kn2) + 1e-8f);
  float sim = 0.0f;
#pragma unroll
  for (int jj = 0; jj < 16; jj++) sim += qsh[wave][jj] * kv[jj];
  sim *= rn;

  float rem = sim;
  float tv[3]; int ti[3];
#pragma unroll
  for (int k = 0; k < 3; k++) {
    float v = rem; int idx = m;
#pragma unroll
    for (int d = 1; d < 64; d <<= 1) {
      float ov = __shfl_xor(v, d);
      int   oi = __shfl_xor(idx, d);
      if (ov > v || (ov == v && oi < idx)) { v = ov; idx = oi; }
    }
    tv[k] = v; ti[k] = idx;
    if (m == idx) rem = -INFINITY;
  }
  float tot = tv[0] + tv[1] + tv[2];

  float ex = 0, ey = 0, ez = 0, ew = 0;
#pragma unroll
  for (int k = 0; k < 3; k++) {
    float4 vv = ld4(vals + (size_t)ti[k] * H_ + lane * 4);
    ex += tv[k] * vv.x; ey += tv[k] * vv.y;
    ez += tv[k] * vv.z; ew += tv[k] * vv.w;
  }
  float inv = (tot > 0.0f) ? 1.0f / tot : 0.0f;
  const float qw = qwp[0];

  float4 o;
  o.x = qw * ex * inv; o.y = qw * ey * inv;
  o.z = qw * ez * inv; o.w = qw * ew * inv;
  *(float4*)&enh[(size_t)t * H_ + lane * 4] = o;
}

// ---------------------------------------------------------------------------
// Final projection, IN-PLACE on io (= d_out). Block owns 64 rows x all 256
// cols; reads its own rows, writes after the K-loop -> race-free in-place.
// ---------------------------------------------------------------------------
__global__ __launch_bounds__(256) void gemm_cat(
    float* __restrict__ io, const float* __restrict__ A2,
    const float* __restrict__ Bw, const float* __restrict__ bias,
    const float* __restrict__ cwp)
{
  __shared__ float As[16][68];
  __shared__ float Bs[16][260];
  const int tid  = threadIdx.x;
  const int row0 = blockIdx.x * 64;
  const int tx = tid & 15, ty = tid >> 4;
  const int lr = tid >> 2;
  const int lk = (tid & 3) << 2;
  const float cw = cwp[0];

  float acc[4][16];
#pragma unroll
  for (int i = 0; i < 4; i++)
#pragma unroll
    for (int j = 0; j < 16; j++) acc[i][j] = 0.0f;

  for (int k0 = 0; k0 < 512; k0 += 16) {
    float4 av;
    if (k0 < 256) {
      av = ld4(io + (size_t)(row0 + lr) * 256 + k0 + lk);
      av.x *= cw; av.y *= cw; av.z *= cw; av.w *= cw;
    } else {
      av = ld4(A2 + (size_t)(row0 + lr) * 256 + (k0 - 256) + lk);
    }
    As[lk + 0][lr] = av.x; As[lk + 1][lr] = av.y;
    As[lk + 2][lr] = av.z; As[lk + 3][lr] = av.w;
    const float* bp = Bw + (size_t)tid * 512 + k0;
#pragma unroll
    for (int q = 0; q < 4; q++) {
      float4 b4 = ld4(bp + 4 * q);
      Bs[4 * q + 0][tid] = b4.x; Bs[4 * q + 1][tid] = b4.y;
      Bs[4 * q + 2][tid] = b4.z; Bs[4 * q + 3][tid] = b4.w;
    }
    __syncthreads();
#pragma unroll
    for (int k = 0; k < 16; k++) {
      float4 a4 = *(const float4*)&As[k][ty << 2];
      float aa[4] = {a4.x, a4.y, a4.z, a4.w};
#pragma unroll
      for (int cc = 0; cc < 4; cc++) {
        float4 b4 = *(const float4*)&Bs[k][cc * 64 + (tx << 2)];
        float bb[4] = {b4.x, b4.y, b4.z, b4.w};
#pragma unroll
        for (int i = 0; i < 4; i++)
#pragma unroll
          for (int jj = 0; jj < 4; jj++) acc[i][cc * 4 + jj] += aa[i] * bb[jj];
      }
    }
    __syncthreads();
  }

#pragma unroll
  for (int i = 0; i < 4; i++) {
#pragma unroll
    for (int cc = 0; cc < 4; cc++) {
      int c0 = cc * 64 + (tx << 2);
      float4 o;
      o.x = acc[i][cc * 4 + 0] + bias[c0 + 0];
      o.y = acc[i][cc * 4 + 1] + bias[c0 + 1];
      o.z = acc[i][cc * 4 + 2] + bias[c0 + 2];
      o.w = acc[i][cc * 4 + 3] + bias[c0 + 3];
      *(float4*)&io[(size_t)(row0 + (ty << 2) + i) * 256 + c0] = o;
    }
  }
}

// ---------------------------------------------------------------------------
extern "C" void kernel_launch(void* const* d_in, const int* in_sizes, int n_in,
                              void* d_out, int out_size, void* d_ws, size_t ws_size,
                              hipStream_t stream)
{
  const float* x    = (const float*)d_in[0];
  const float* Wih0 = (const float*)d_in[1];
  const float* Whh0 = (const float*)d_in[2];
  const float* bih0 = (const float*)d_in[3];
  const float* bhh0 = (const float*)d_in[4];
  const float* Wih1 = (const float*)d_in[5];
  const float* Whh1 = (const float*)d_in[6];
  const float* bih1 = (const float*)d_in[7];
  const float* bhh1 = (const float*)d_in[8];
  const float* Wcq  = (const float*)d_in[9];
  const float* bcq  = (const float*)d_in[10];
  const float* keys = (const float*)d_in[11];
  const float* vals = (const float*)d_in[12];
  const float* Wout = (const float*)d_in[13];
  const float* bout = (const float*)d_in[14];
  const float* cw   = (const float*)d_in[15];
  const float* qw   = (const float*)d_in[16];
  float* out = (float*)d_out;

  // ws: [exchange 256 KB (dead after lstm2)] overlapped with enh [MT,256] f32.
  const size_t HE = (size_t)B_ * S_ * H_;
  if (ws_size < HE * sizeof(float)) return;   // 67.1 MB (round-4 proven OK)
  u64* exs = (u64*)d_ws;
  float* enh = (float*)d_ws;

  const int MT = B_ * S_;

  hipMemsetAsync(exs, 0, (size_t)32 * 1024 * sizeof(u64), stream);
  lstm2<<<dim3(512), dim3(256), 0, stream>>>(x, Wih0, bih0, bhh0, Whh0,
                                             Wih1, bih1, bhh1, Whh1, out, exs);

  knn_enh<<<dim3(MT / 4), dim3(256), 0, stream>>>(out, Wcq, bcq, keys, vals, qw, enh);

  gemm_cat<<<dim3(MT / 64), dim3(256), 0, stream>>>(out, enh, Wout, bout, cw);
}